// Round 5
// baseline (60.690 us; speedup 1.0000x reference)
//
#include <hip/hip_runtime.h>

// Problem constants (K=32, T=16, n=4, L=4 → quadratic-relaxation branch)
static constexpr int       KT     = 512;         // K*T
static constexpr int       TROWS  = 1025;        // 2*K*T + 1 rows in under/over
static constexpr long long PAIRS  = 1050625LL;   // TROWS^2
static constexpr long long ROWSO  = 1051651LL;   // PAIRS + TROWS + 1
static constexpr long long RUF    = ROWSO * 28;  // floats per output tensor
static constexpr long long CHUNKS = PAIRS * 7;   // float4 chunks in the pair region
static constexpr int       NB     = 4105;        // ceil(CHUNKS/1792) pair-blocks per sel
static constexpr int       NTAIL  = 5;           // tail blocks per sel (1034 ids)

// workspace layout (floats): "squared-form" row images + scalars
// SQ row v: [c0, 3*c1, 3*c2, c3] * (v==0 ? sqrt(A_sel) : 1), weight applied.
static constexpr int WS_SQ_U = 0;                // 1025*16
static constexpr int WS_SQ_O = TROWS * 16;       // 16400
static constexpr int WS_SCAL = 2 * TROWS * 16;   // 32800 : [B_u, C_u, B_o, C_o]

__device__ __forceinline__ void row_interval(const float q[16], float& Lr, float& Ur)
{
    float L_ = fminf(fminf(q[0], q[1]), fminf(q[2], q[3]));
    float U_ = fmaxf(fmaxf(q[0], q[1]), fmaxf(q[2], q[3]));
#pragma unroll
    for (int v = 1; v < 4; ++v) {
        const float a0 = q[4*v+0], a1 = q[4*v+1], a2 = q[4*v+2], a3 = q[4*v+3];
        const float lo = fminf(fminf(a0, a1), fminf(a2, a3));
        const float hi = fmaxf(fmaxf(a0, a1), fmaxf(a2, a3));
        const float c0 = L_*lo, c1 = L_*hi, c2 = U_*lo, c3 = U_*hi;
        L_ = fminf(fminf(c0, c1), fminf(c2, c3));
        U_ = fmaxf(fmaxf(c0, c1), fmaxf(c2, c3));
    }
    Lr = L_; Ur = U_;
}

// Phase A: interval bounds l,u → relaxation scalars; then write squared-form
// row images (weights + [1,3,3,1] + sqrt(A) on var0 pre-folded).
__global__ __launch_bounds__(1024)
void phaseA(const float* __restrict__ iu, const float* __restrict__ io,
            const float* __restrict__ posw, const float* __restrict__ negw,
            const float* __restrict__ biasp, float* __restrict__ ws)
{
    __shared__ float sl[16], su[16], sA[2];
    const int t = threadIdx.x;            // row 0..1023 (row 1024 handled by t==0)
    const float bias = biasp[0];

    const float* src = (t < KT) ? io : iu;
    const int s  = (t < KT) ? t : t - KT;
    const int k  = s >> 4;

    const float4* rp = (const float4*)(src + s * 16);
    const float4 r0 = rp[0], r1 = rp[1], r2 = rp[2], r3 = rp[3];
    const float p[16] = { r0.x, r0.y, r0.z, r0.w, r1.x, r1.y, r1.z, r1.w,
                          r2.x, r2.y, r2.z, r2.w, r3.x, r3.y, r3.z, r3.w };

    const float wU = (t < KT) ? negw[k] : posw[k];  // under: [io*neg ; iu*pos]
    const float wO = (t < KT) ? posw[k] : negw[k];  // over : [io*pos ; iu*neg]

    float un[16], ov[16];
#pragma unroll
    for (int i = 0; i < 16; ++i) {
        const float sU = (i < 4) ? wU : 1.0f;   // weight applies to variable 0 only
        const float sO = (i < 4) ? wO : 1.0f;
        un[i] = p[i] * sU;
        ov[i] = p[i] * sO;
    }

    float Lu, Uu, Lo, Uo;
    row_interval(un, Lu, Uu);
    row_interval(ov, Lo, Uo);
    float accL = Lu;   // lower bound contribution (under)
    float accU = Uo;   // upper bound contribution (over)
#pragma unroll
    for (int off = 32; off > 0; off >>= 1) {
        accL += __shfl_down(accL, off, 64);
        accU += __shfl_down(accU, off, 64);
    }
    if ((t & 63) == 0) { sl[t >> 6] = accL; su[t >> 6] = accU; }
    __syncthreads();
    if (t == 0) {
        float l = bias, u = bias;   // const row contributes [bias,bias]
#pragma unroll
        for (int w = 0; w < 16; ++w) { l += sl[w]; u += su[w]; }
        const float d    = u - l;
        const float inv  = 1.0f / d;
        const float inv2 = inv * inv;
        const float A_u  = inv;                 // cu.a  (>0 since u>l)
        const float A_o  = u * inv2;            // co.a  (>0 since u>0)
        ws[WS_SCAL + 0] = -l * inv;             // B_u
        ws[WS_SCAL + 1] = 0.0f;                 // C_u
        ws[WS_SCAL + 2] = -2.0f * u * l * inv2; // B_o
        ws[WS_SCAL + 3] = u * l * l * inv2;     // C_o
        sA[0] = sqrtf(A_u);
        sA[1] = sqrtf(A_o);
    }
    __syncthreads();
    const float qU = sA[0], qO = sA[1];

    // squared-form rows for this thread's row t
    float4* du = (float4*)(ws + WS_SQ_U + t * 16);
    float4* dov= (float4*)(ws + WS_SQ_O + t * 16);
#pragma unroll
    for (int v = 0; v < 4; ++v) {
        const float mU = (v == 0) ? qU : 1.0f;
        const float mO = (v == 0) ? qO : 1.0f;
        du[v]  = make_float4(un[4*v]*mU, 3.f*un[4*v+1]*mU, 3.f*un[4*v+2]*mU, un[4*v+3]*mU);
        dov[v] = make_float4(ov[4*v]*mO, 3.f*ov[4*v+1]*mO, 3.f*ov[4*v+2]*mO, ov[4*v+3]*mO);
    }
    if (t == 0) {
        // const row 1024: var0 = bias, others = 1
        float4* cu4 = (float4*)(ws + WS_SQ_U + 1024 * 16);
        float4* co4 = (float4*)(ws + WS_SQ_O + 1024 * 16);
#pragma unroll
        for (int v = 0; v < 4; ++v) {
            const float base = (v == 0) ? bias : 1.0f;
            const float mU = (v == 0) ? qU : 1.0f;
            const float mO = (v == 0) ? qO : 1.0f;
            cu4[v] = make_float4(base*mU, 3.f*base*mU, 3.f*base*mU, base*mU);
            co4[v] = make_float4(base*mO, 3.f*base*mO, 3.f*base*mO, base*mO);
        }
    }
}

// Phase B+C fused, direct-store version: no LDS, no barriers.
// Pair blocks: thread computes output float4-chunk c directly and stores it
// coalesced (lane-consecutive chunks). Tail blocks: elevation rows rebuilt
// from raw inputs, const row, deg outputs.
__global__ __launch_bounds__(256)
void phaseBC(const float* __restrict__ ws,
             const int* __restrict__ degu, const int* __restrict__ dego,
             const float* __restrict__ posw, const float* __restrict__ negw,
             const float* __restrict__ biasp,
             const float* __restrict__ iu, const float* __restrict__ io,
             float* __restrict__ out)
{
    const int t   = threadIdx.x;
    const int bx  = blockIdx.x;
    const int sel = blockIdx.y;              // 0 = ru/under/cu, 1 = ro/over/co
    float* outT = out + (long long)sel * RUF;

    if (bx >= NB) {
        // ---- tail: elevation rows + const row + deg outputs ----
        const int id2 = (bx - NB) * 256 + t;
        const float B = ws[WS_SCAL + sel * 2 + 0];
        const float C = ws[WS_SCAL + sel * 2 + 1];
        if (id2 <= TROWS) {
            float o[28];
            if (id2 < TROWS) {
                // rebuild original (weighted) row id2 from raw inputs
                float raw[16];
                float w;
                if (id2 < 1024) {
                    const float* src = (id2 < KT) ? io : iu;
                    const int s2 = (id2 < KT) ? id2 : id2 - KT;
                    const int k2 = s2 >> 4;
                    const float4* rp = (const float4*)(src + s2 * 16);
#pragma unroll
                    for (int v = 0; v < 4; ++v) {
                        const float4 rv = rp[v];
                        raw[4*v+0] = rv.x; raw[4*v+1] = rv.y;
                        raw[4*v+2] = rv.z; raw[4*v+3] = rv.w;
                    }
                    const bool isIo = (id2 < KT);
                    w = (sel == 0) ? (isIo ? negw[k2] : posw[k2])
                                   : (isIo ? posw[k2] : negw[k2]);
                } else {
                    const float bias = biasp[0];
#pragma unroll
                    for (int i = 0; i < 16; ++i) raw[i] = (i < 4) ? bias : 1.0f;
                    w = 1.0f;
                }
#pragma unroll
                for (int v = 0; v < 4; ++v) {
                    const float sB = (v == 0) ? w * B : 1.0f;
                    const float q0 = raw[4*v+0]*sB, q1 = raw[4*v+1]*sB;
                    const float q2 = raw[4*v+2]*sB, q3 = raw[4*v+3]*sB;
                    // Bernstein degree elevation 3 -> 6
                    o[7*v+0] = q0;
                    o[7*v+1] = 0.5f*(q0 + q1);
                    o[7*v+2] = 0.2f*q0 + 0.6f*q1 + 0.2f*q2;
                    o[7*v+3] = 0.05f*q0 + 0.45f*q1 + 0.45f*q2 + 0.05f*q3;
                    o[7*v+4] = 0.2f*q1 + 0.6f*q2 + 0.2f*q3;
                    o[7*v+5] = 0.5f*(q2 + q3);
                    o[7*v+6] = q3;
                }
            } else {
                // const-term row: var0 = C everywhere, others = 1
#pragma unroll
                for (int j = 0; j < 28; ++j) o[j] = (j < 7) ? C : 1.0f;
            }
            float* dst = outT + (PAIRS + (long long)id2) * 28LL;
#pragma unroll
            for (int j = 0; j < 28; ++j) dst[j] = o[j];
        } else if (sel == 0 && id2 >= TROWS + 1 && id2 < TROWS + 9) {
            const int j = id2 - (TROWS + 1);
            const int v = j & 3;
            int m = 0;
            for (int kk = 0; kk < 32; ++kk)
                m = max(m, max(degu[kk * 4 + v], dego[kk * 4 + v]));
            out[2 * RUF + j] = 2.0f * (float)m;   // out[2] (j<4) and out[3] (j>=4)
        }
        return;
    }

    // ---- pair blocks: direct chunk-mapped Bernstein square ----
    const float4* SQ = (const float4*)(ws + sel * WS_SQ_O);
    const long long cbase = (long long)bx * 1792;

#pragma unroll
    for (int it = 0; it < 7; ++it) {
        const long long c = cbase + it * 256 + t;
        if (c < CHUNKS) {
            const unsigned cc = (unsigned)c;
            const unsigned r  = cc / 7u;
            const int      q  = (int)(cc - r * 7u);
            const unsigned a  = r / 1025u;
            const unsigned b  = r - a * 1025u;

            const int vA = q >> 1;                    // 0,0,1,1,2,2,3
            const int o  = (q & 1) ? (vA + 4) : vA;   // 0,4,1,5,2,6,3
            const int vB = (vA < 3) ? vA + 1 : 3;

            const float4 fa = SQ[a * 4 + vA];
            const float4 fb = SQ[b * 4 + vA];
            const float4 ga = SQ[a * 4 + vB];
            const float4 gb = SQ[b * 4 + vB];

            // conv of squared-form rows (scales/binoms pre-folded except 1/binom2)
            const float l0 = fa.x*fb.x;
            const float l1 = (fa.x*fb.y + fa.y*fb.x) * (1.f/6.f);
            const float l2 = (fa.x*fb.z + fa.y*fb.y + fa.z*fb.x) * (1.f/15.f);
            const float l3 = (fa.x*fb.w + fa.y*fb.z + fa.z*fb.y + fa.w*fb.x) * 0.05f;
            const float l4 = (fa.y*fb.w + fa.z*fb.z + fa.w*fb.y) * (1.f/15.f);
            const float l5 = (fa.z*fb.w + fa.w*fb.z) * (1.f/6.f);
            const float l6 = fa.w*fb.w;
            const float h0 = ga.x*gb.x;
            const float h1 = (ga.x*gb.y + ga.y*gb.x) * (1.f/6.f);
            const float h2 = (ga.x*gb.z + ga.y*gb.y + ga.z*gb.x) * (1.f/15.f);

            float rr[4];
#pragma unroll
            for (int e = 0; e < 4; ++e) {
                const int kk = o + e;     // 0..9
                float x = l0;
                x = (kk == 1) ? l1 : x;
                x = (kk == 2) ? l2 : x;
                x = (kk == 3) ? l3 : x;
                x = (kk == 4) ? l4 : x;
                x = (kk == 5) ? l5 : x;
                x = (kk == 6) ? l6 : x;
                x = (kk == 7) ? h0 : x;
                x = (kk == 8) ? h1 : x;
                x = (kk == 9) ? h2 : x;
                rr[e] = x;
            }
            ((float4*)outT)[c] = make_float4(rr[0], rr[1], rr[2], rr[3]);
        }
    }
}

extern "C" void kernel_launch(void* const* d_in, const int* in_sizes, int n_in,
                              void* d_out, int out_size, void* d_ws, size_t ws_size,
                              hipStream_t stream)
{
    const float* iu   = (const float*)d_in[0];
    const float* io   = (const float*)d_in[1];
    const int*   degu = (const int*)d_in[2];
    const int*   dego = (const int*)d_in[3];
    const float* posw = (const float*)d_in[4];
    const float* negw = (const float*)d_in[5];
    const float* bias = (const float*)d_in[6];
    float* out = (float*)d_out;
    float* ws  = (float*)d_ws;

    hipLaunchKernelGGL(phaseA, dim3(1), dim3(1024), 0, stream,
                       iu, io, posw, negw, bias, ws);

    hipLaunchKernelGGL(phaseBC, dim3(NB + NTAIL, 2), dim3(256), 0, stream,
                       ws, degu, dego, posw, negw, bias, iu, io, out);
}

// Round 7
// 60.555 us; speedup vs baseline: 1.0022x; 1.0022x over previous
//
#include <hip/hip_runtime.h>

typedef float f32x4 __attribute__((ext_vector_type(4)));

// Problem constants (K=32, T=16, n=4, L=4 → quadratic-relaxation branch)
static constexpr int       KT    = 512;         // K*T
static constexpr int       TROWS = 1025;        // 2*K*T + 1 rows in under/over
static constexpr long long PAIRS = 1050625LL;   // TROWS^2
static constexpr long long ROWSO = 1051651LL;   // PAIRS + TROWS + 1
static constexpr long long RUF   = ROWSO * 28;  // floats per output tensor
static constexpr int       NB    = 4105;        // ceil(PAIRS/256) pair-blocks per sel
static constexpr int       NTAIL = 5;           // tail blocks per sel

// workspace layout (floats)
static constexpr int WS_UNDER = 0;
static constexpr int WS_OVER  = TROWS * 16;      // 16400
static constexpr int WS_SCAL  = 2 * TROWS * 16;  // 32800 : cu[3], co[3]

__device__ __forceinline__ void row_interval(const float q[16], float& Lr, float& Ur)
{
    float L_ = fminf(fminf(q[0], q[1]), fminf(q[2], q[3]));
    float U_ = fmaxf(fmaxf(q[0], q[1]), fmaxf(q[2], q[3]));
#pragma unroll
    for (int v = 1; v < 4; ++v) {
        const float a0 = q[4*v+0], a1 = q[4*v+1], a2 = q[4*v+2], a3 = q[4*v+3];
        const float lo = fminf(fminf(a0, a1), fminf(a2, a3));
        const float hi = fmaxf(fmaxf(a0, a1), fmaxf(a2, a3));
        const float c0 = L_*lo, c1 = L_*hi, c2 = U_*lo, c3 = U_*hi;
        L_ = fminf(fminf(c0, c1), fminf(c2, c3));
        U_ = fmaxf(fmaxf(c0, c1), fmaxf(c2, c3));
    }
    Lr = L_; Ur = U_;
}

// Phase A: build under/over rows, interval bounds l,u, relaxation coefficients.
// Single block, 1024 threads; one barrier (wave-shuffle reduction).
__global__ __launch_bounds__(1024)
void phaseA(const float* __restrict__ iu, const float* __restrict__ io,
            const float* __restrict__ posw, const float* __restrict__ negw,
            const float* __restrict__ biasp, float* __restrict__ ws)
{
    __shared__ float sl[16];
    __shared__ float su[16];
    const int t = threadIdx.x;            // row 0..1023 (row 1024 handled by t==0)
    const float bias = biasp[0];

    const float* src = (t < KT) ? io : iu;
    const int s  = (t < KT) ? t : t - KT;
    const int k  = s >> 4;

    const float4* rp = (const float4*)(src + s * 16);
    const float4 r0 = rp[0], r1 = rp[1], r2 = rp[2], r3 = rp[3];
    const float p[16] = { r0.x, r0.y, r0.z, r0.w, r1.x, r1.y, r1.z, r1.w,
                          r2.x, r2.y, r2.z, r2.w, r3.x, r3.y, r3.z, r3.w };

    const float wU = (t < KT) ? negw[k] : posw[k];  // under: [io*neg ; iu*pos]
    const float wO = (t < KT) ? posw[k] : negw[k];  // over : [io*pos ; iu*neg]

    float un[16], ov[16];
#pragma unroll
    for (int i = 0; i < 16; ++i) {
        const float sU = (i < 4) ? wU : 1.0f;   // weight applies to variable 0 only
        const float sO = (i < 4) ? wO : 1.0f;
        un[i] = p[i] * sU;
        ov[i] = p[i] * sO;
    }
    float4* wu4 = (float4*)(ws + WS_UNDER + t * 16);
    float4* wo4 = (float4*)(ws + WS_OVER  + t * 16);
#pragma unroll
    for (int i = 0; i < 4; ++i) {
        wu4[i] = make_float4(un[4*i], un[4*i+1], un[4*i+2], un[4*i+3]);
        wo4[i] = make_float4(ov[4*i], ov[4*i+1], ov[4*i+2], ov[4*i+3]);
    }

    float Lu, Uu, Lo, Uo;
    row_interval(un, Lu, Uu);
    row_interval(ov, Lo, Uo);
    float accL = Lu;   // lower bound contribution (under)
    float accU = Uo;   // upper bound contribution (over)
#pragma unroll
    for (int off = 32; off > 0; off >>= 1) {
        accL += __shfl_down(accL, off, 64);
        accU += __shfl_down(accU, off, 64);
    }
    if ((t & 63) == 0) { sl[t >> 6] = accL; su[t >> 6] = accU; }
    __syncthreads();
    if (t == 0) {
        // const row (index 1024): var0 = bias everywhere, others = 1
#pragma unroll
        for (int i = 0; i < 16; ++i) {
            const float cv = (i < 4) ? bias : 1.0f;
            ws[WS_UNDER + 1024 * 16 + i] = cv;
            ws[WS_OVER  + 1024 * 16 + i] = cv;
        }
        float l = bias, u = bias;   // const row contributes [bias,bias]
#pragma unroll
        for (int w = 0; w < 16; ++w) { l += sl[w]; u += su[w]; }
        const float d    = u - l;
        const float inv  = 1.0f / d;
        const float inv2 = inv * inv;
        ws[WS_SCAL + 0] = inv;                 // cu.a
        ws[WS_SCAL + 1] = -l * inv;            // cu.b
        ws[WS_SCAL + 2] = 0.0f;                // cu.c
        ws[WS_SCAL + 3] = u * inv2;            // co.a
        ws[WS_SCAL + 4] = -2.0f * u * l * inv2;// co.b
        ws[WS_SCAL + 5] = u * l * l * inv2;    // co.c
    }
}

// Phase B+C fused. Pair-blocks: Bernstein square with 16B-aligned, XOR-swizzled
// LDS staging (7 ds_write_b128 + 7 ds_read_b128 per thread instead of 28+28
// scalar ops at stride-29), then fully coalesced nt stores.
// LDS row: pair p owns 32 floats; chunk q lives at 16B-slot (q ^ (p&7)).
__global__ __launch_bounds__(256)
void phaseBC(const float* __restrict__ ws,
             const int* __restrict__ degu, const int* __restrict__ dego,
             float* __restrict__ out)
{
    __shared__ f32x4 lds[256 * 8];           // 32 KiB
    const int t   = threadIdx.x;
    const int bx  = blockIdx.x;
    const int sel = blockIdx.y;              // 0 = ru/under/cu, 1 = ro/over/co
    float* outT = out + (long long)sel * RUF;

    if (bx >= NB) {
        // ---- tail: elevation rows + const row + deg outputs ----
        const int id2 = (bx - NB) * 256 + t;
        const float B = ws[WS_SCAL + sel * 3 + 1];
        const float C = ws[WS_SCAL + sel * 3 + 2];
        if (id2 <= TROWS) {
            float o[28];
            if (id2 < TROWS) {
                const float* P = ws + sel * WS_OVER + id2 * 16;
#pragma unroll
                for (int v = 0; v < 4; ++v) {
                    const float sB = (v == 0) ? B : 1.0f;
                    const float q0 = P[4*v+0]*sB, q1 = P[4*v+1]*sB;
                    const float q2 = P[4*v+2]*sB, q3 = P[4*v+3]*sB;
                    // Bernstein degree elevation 3 -> 6
                    o[7*v+0] = q0;
                    o[7*v+1] = 0.5f*(q0 + q1);
                    o[7*v+2] = 0.2f*q0 + 0.6f*q1 + 0.2f*q2;
                    o[7*v+3] = 0.05f*q0 + 0.45f*q1 + 0.45f*q2 + 0.05f*q3;
                    o[7*v+4] = 0.2f*q1 + 0.6f*q2 + 0.2f*q3;
                    o[7*v+5] = 0.5f*(q2 + q3);
                    o[7*v+6] = q3;
                }
            } else {
                // const-term row: var0 = C everywhere, others = 1
#pragma unroll
                for (int j = 0; j < 28; ++j) o[j] = (j < 7) ? C : 1.0f;
            }
            float* dst = outT + (PAIRS + (long long)id2) * 28LL;
#pragma unroll
            for (int j = 0; j < 28; ++j) dst[j] = o[j];
        } else if (sel == 0 && id2 >= TROWS + 1 && id2 < TROWS + 9) {
            const int j = id2 - (TROWS + 1);
            const int v = j & 3;
            int m = 0;
            for (int kk = 0; kk < 32; ++kk)
                m = max(m, max(degu[kk * 4 + v], dego[kk * 4 + v]));
            out[2 * RUF + j] = 2.0f * (float)m;   // out[2] (j<4) and out[3] (j>=4)
        }
        return;
    }

    // ---- pair blocks: Bernstein square ----
    const long long blockPair = (long long)bx * 256;
    const long long idx = blockPair + t;

    const float* P = ws + sel * WS_OVER;
    const float  A = ws[WS_SCAL + sel * 3];

    if (idx < PAIRS) {
        const unsigned r = (unsigned)idx;
        const unsigned a = r / 1025u;
        const unsigned b = r - a * 1025u;
        const float* pa = P + a * 16;
        const float* pb = P + b * 16;

        float o[28];
#pragma unroll
        for (int v = 0; v < 4; ++v) {
            const float wa0 = pa[4*v+0],       wa1 = pa[4*v+1] * 3.f;
            const float wa2 = pa[4*v+2] * 3.f, wa3 = pa[4*v+3];
            const float wb0 = pb[4*v+0],       wb1 = pb[4*v+1] * 3.f;
            const float wb2 = pb[4*v+2] * 3.f, wb3 = pb[4*v+3];
            const float sA = (v == 0) ? A : 1.0f;
            o[7*v+0] = (wa0*wb0) * sA;
            o[7*v+1] = (wa0*wb1 + wa1*wb0) * (sA * (1.f/6.f));
            o[7*v+2] = (wa0*wb2 + wa1*wb1 + wa2*wb0) * (sA * (1.f/15.f));
            o[7*v+3] = (wa0*wb3 + wa1*wb2 + wa2*wb1 + wa3*wb0) * (sA * 0.05f);
            o[7*v+4] = (wa1*wb3 + wa2*wb2 + wa3*wb1) * (sA * (1.f/15.f));
            o[7*v+5] = (wa2*wb3 + wa3*wb2) * (sA * (1.f/6.f));
            o[7*v+6] = (wa3*wb3) * sA;
        }
        // 7 aligned b128 writes, slot XOR-swizzled to spread banks
        const int sw = t & 7;
#pragma unroll
        for (int q = 0; q < 7; ++q) {
            f32x4 vv;
            vv.x = o[4*q+0]; vv.y = o[4*q+1]; vv.z = o[4*q+2]; vv.w = o[4*q+3];
            lds[t * 8 + (q ^ sw)] = vv;
        }
    }
    __syncthreads();

    // Coalesced nt drain: 1792 float4-chunks per block, 7 per thread.
    const long long totalChunks = PAIRS * 7;
#pragma unroll
    for (int it = 0; it < 7; ++it) {
        const int local = it * 256 + t;          // 0..1791 chunk within block
        const long long c = blockPair * 7 + local;
        if (c < totalChunks) {
            const int p = local / 7;             // pair within block (magic-mul)
            const int q = local - p * 7;         // float4 index within pair
            const f32x4 vv = lds[p * 8 + (q ^ (p & 7))];
            __builtin_nontemporal_store(vv, ((f32x4*)outT) + c);
        }
    }
}

extern "C" void kernel_launch(void* const* d_in, const int* in_sizes, int n_in,
                              void* d_out, int out_size, void* d_ws, size_t ws_size,
                              hipStream_t stream)
{
    const float* iu   = (const float*)d_in[0];
    const float* io   = (const float*)d_in[1];
    const int*   degu = (const int*)d_in[2];
    const int*   dego = (const int*)d_in[3];
    const float* posw = (const float*)d_in[4];
    const float* negw = (const float*)d_in[5];
    const float* bias = (const float*)d_in[6];
    float* out = (float*)d_out;
    float* ws  = (float*)d_ws;

    hipLaunchKernelGGL(phaseA, dim3(1), dim3(1024), 0, stream,
                       iu, io, posw, negw, bias, ws);

    hipLaunchKernelGGL(phaseBC, dim3(NB + NTAIL, 2), dim3(256), 0, stream,
                       ws, degu, dego, out);
}

// Round 8
// 48.044 us; speedup vs baseline: 1.2632x; 1.2604x over previous
//
#include <hip/hip_runtime.h>

typedef float f32x4 __attribute__((ext_vector_type(4)));

// Problem constants (K=32, T=16, n=4, L=4 → quadratic-relaxation branch)
static constexpr int       KT    = 512;         // K*T
static constexpr int       TROWS = 1025;        // 2*K*T + 1 rows in under/over
static constexpr long long PAIRS = 1050625LL;   // TROWS^2
static constexpr long long ROWSO = 1051651LL;   // PAIRS + TROWS + 1
static constexpr long long RUF   = ROWSO * 28;  // floats per output tensor
static constexpr int       NB    = 4105;        // ceil(PAIRS/256) pair-blocks per sel
static constexpr int       NTAIL = 5;           // tail blocks per sel

// workspace layout (floats)
static constexpr int WS_UNDER = 0;
static constexpr int WS_OVER  = TROWS * 16;      // 16400
static constexpr int WS_SCAL  = 2 * TROWS * 16;  // 32800 : cu[3], co[3]

__device__ __forceinline__ void row_interval(const float q[16], float& Lr, float& Ur)
{
    float L_ = fminf(fminf(q[0], q[1]), fminf(q[2], q[3]));
    float U_ = fmaxf(fmaxf(q[0], q[1]), fmaxf(q[2], q[3]));
#pragma unroll
    for (int v = 1; v < 4; ++v) {
        const float a0 = q[4*v+0], a1 = q[4*v+1], a2 = q[4*v+2], a3 = q[4*v+3];
        const float lo = fminf(fminf(a0, a1), fminf(a2, a3));
        const float hi = fmaxf(fmaxf(a0, a1), fmaxf(a2, a3));
        const float c0 = L_*lo, c1 = L_*hi, c2 = U_*lo, c3 = U_*hi;
        L_ = fminf(fminf(c0, c1), fminf(c2, c3));
        U_ = fmaxf(fmaxf(c0, c1), fmaxf(c2, c3));
    }
    Lr = L_; Ur = U_;
}

// Phase A: build under/over rows, interval bounds l,u, relaxation coefficients.
// Single block, 1024 threads; one barrier (wave-shuffle reduction).
__global__ __launch_bounds__(1024)
void phaseA(const float* __restrict__ iu, const float* __restrict__ io,
            const float* __restrict__ posw, const float* __restrict__ negw,
            const float* __restrict__ biasp, float* __restrict__ ws)
{
    __shared__ float sl[16];
    __shared__ float su[16];
    const int t = threadIdx.x;            // row 0..1023 (row 1024 handled by t==0)
    const float bias = biasp[0];

    const float* src = (t < KT) ? io : iu;
    const int s  = (t < KT) ? t : t - KT;
    const int k  = s >> 4;

    const float4* rp = (const float4*)(src + s * 16);
    const float4 r0 = rp[0], r1 = rp[1], r2 = rp[2], r3 = rp[3];
    const float p[16] = { r0.x, r0.y, r0.z, r0.w, r1.x, r1.y, r1.z, r1.w,
                          r2.x, r2.y, r2.z, r2.w, r3.x, r3.y, r3.z, r3.w };

    const float wU = (t < KT) ? negw[k] : posw[k];  // under: [io*neg ; iu*pos]
    const float wO = (t < KT) ? posw[k] : negw[k];  // over : [io*pos ; iu*neg]

    float un[16], ov[16];
#pragma unroll
    for (int i = 0; i < 16; ++i) {
        const float sU = (i < 4) ? wU : 1.0f;   // weight applies to variable 0 only
        const float sO = (i < 4) ? wO : 1.0f;
        un[i] = p[i] * sU;
        ov[i] = p[i] * sO;
    }
    float4* wu4 = (float4*)(ws + WS_UNDER + t * 16);
    float4* wo4 = (float4*)(ws + WS_OVER  + t * 16);
#pragma unroll
    for (int i = 0; i < 4; ++i) {
        wu4[i] = make_float4(un[4*i], un[4*i+1], un[4*i+2], un[4*i+3]);
        wo4[i] = make_float4(ov[4*i], ov[4*i+1], ov[4*i+2], ov[4*i+3]);
    }

    float Lu, Uu, Lo, Uo;
    row_interval(un, Lu, Uu);
    row_interval(ov, Lo, Uo);
    float accL = Lu;   // lower bound contribution (under)
    float accU = Uo;   // upper bound contribution (over)
#pragma unroll
    for (int off = 32; off > 0; off >>= 1) {
        accL += __shfl_down(accL, off, 64);
        accU += __shfl_down(accU, off, 64);
    }
    if ((t & 63) == 0) { sl[t >> 6] = accL; su[t >> 6] = accU; }
    __syncthreads();
    if (t == 0) {
        // const row (index 1024): var0 = bias everywhere, others = 1
#pragma unroll
        for (int i = 0; i < 16; ++i) {
            const float cv = (i < 4) ? bias : 1.0f;
            ws[WS_UNDER + 1024 * 16 + i] = cv;
            ws[WS_OVER  + 1024 * 16 + i] = cv;
        }
        float l = bias, u = bias;   // const row contributes [bias,bias]
#pragma unroll
        for (int w = 0; w < 16; ++w) { l += sl[w]; u += su[w]; }
        const float d    = u - l;
        const float inv  = 1.0f / d;
        const float inv2 = inv * inv;
        ws[WS_SCAL + 0] = inv;                 // cu.a
        ws[WS_SCAL + 1] = -l * inv;            // cu.b
        ws[WS_SCAL + 2] = 0.0f;                // cu.c
        ws[WS_SCAL + 3] = u * inv2;            // co.a
        ws[WS_SCAL + 4] = -2.0f * u * l * inv2;// co.b
        ws[WS_SCAL + 5] = u * l * l * inv2;    // co.c
    }
}

// Phase B+C fused. Pair-blocks: Bernstein square with 16B-aligned, XOR-swizzled
// LDS staging (7 ds_write_b128 + 7 ds_read_b128 per thread), then fully
// coalesced PLAIN stores (L2 write-combines to full HBM lines; nt hurt -25%).
// LDS row: pair p owns 32 floats; chunk q lives at 16B-slot (q ^ (p&7)).
__global__ __launch_bounds__(256)
void phaseBC(const float* __restrict__ ws,
             const int* __restrict__ degu, const int* __restrict__ dego,
             float* __restrict__ out)
{
    __shared__ f32x4 lds[256 * 8];           // 32 KiB
    const int t   = threadIdx.x;
    const int bx  = blockIdx.x;
    const int sel = blockIdx.y;              // 0 = ru/under/cu, 1 = ro/over/co
    float* outT = out + (long long)sel * RUF;

    if (bx >= NB) {
        // ---- tail: elevation rows + const row + deg outputs ----
        const int id2 = (bx - NB) * 256 + t;
        const float B = ws[WS_SCAL + sel * 3 + 1];
        const float C = ws[WS_SCAL + sel * 3 + 2];
        if (id2 <= TROWS) {
            float o[28];
            if (id2 < TROWS) {
                const float* P = ws + sel * WS_OVER + id2 * 16;
#pragma unroll
                for (int v = 0; v < 4; ++v) {
                    const float sB = (v == 0) ? B : 1.0f;
                    const float q0 = P[4*v+0]*sB, q1 = P[4*v+1]*sB;
                    const float q2 = P[4*v+2]*sB, q3 = P[4*v+3]*sB;
                    // Bernstein degree elevation 3 -> 6
                    o[7*v+0] = q0;
                    o[7*v+1] = 0.5f*(q0 + q1);
                    o[7*v+2] = 0.2f*q0 + 0.6f*q1 + 0.2f*q2;
                    o[7*v+3] = 0.05f*q0 + 0.45f*q1 + 0.45f*q2 + 0.05f*q3;
                    o[7*v+4] = 0.2f*q1 + 0.6f*q2 + 0.2f*q3;
                    o[7*v+5] = 0.5f*(q2 + q3);
                    o[7*v+6] = q3;
                }
            } else {
                // const-term row: var0 = C everywhere, others = 1
#pragma unroll
                for (int j = 0; j < 28; ++j) o[j] = (j < 7) ? C : 1.0f;
            }
            float* dst = outT + (PAIRS + (long long)id2) * 28LL;
#pragma unroll
            for (int j = 0; j < 28; ++j) dst[j] = o[j];
        } else if (sel == 0 && id2 >= TROWS + 1 && id2 < TROWS + 9) {
            const int j = id2 - (TROWS + 1);
            const int v = j & 3;
            int m = 0;
            for (int kk = 0; kk < 32; ++kk)
                m = max(m, max(degu[kk * 4 + v], dego[kk * 4 + v]));
            out[2 * RUF + j] = 2.0f * (float)m;   // out[2] (j<4) and out[3] (j>=4)
        }
        return;
    }

    // ---- pair blocks: Bernstein square ----
    const long long blockPair = (long long)bx * 256;
    const long long idx = blockPair + t;

    const float* P = ws + sel * WS_OVER;
    const float  A = ws[WS_SCAL + sel * 3];

    if (idx < PAIRS) {
        const unsigned r = (unsigned)idx;
        const unsigned a = r / 1025u;
        const unsigned b = r - a * 1025u;
        const float* pa = P + a * 16;
        const float* pb = P + b * 16;

        float o[28];
#pragma unroll
        for (int v = 0; v < 4; ++v) {
            const float wa0 = pa[4*v+0],       wa1 = pa[4*v+1] * 3.f;
            const float wa2 = pa[4*v+2] * 3.f, wa3 = pa[4*v+3];
            const float wb0 = pb[4*v+0],       wb1 = pb[4*v+1] * 3.f;
            const float wb2 = pb[4*v+2] * 3.f, wb3 = pb[4*v+3];
            const float sA = (v == 0) ? A : 1.0f;
            o[7*v+0] = (wa0*wb0) * sA;
            o[7*v+1] = (wa0*wb1 + wa1*wb0) * (sA * (1.f/6.f));
            o[7*v+2] = (wa0*wb2 + wa1*wb1 + wa2*wb0) * (sA * (1.f/15.f));
            o[7*v+3] = (wa0*wb3 + wa1*wb2 + wa2*wb1 + wa3*wb0) * (sA * 0.05f);
            o[7*v+4] = (wa1*wb3 + wa2*wb2 + wa3*wb1) * (sA * (1.f/15.f));
            o[7*v+5] = (wa2*wb3 + wa3*wb2) * (sA * (1.f/6.f));
            o[7*v+6] = (wa3*wb3) * sA;
        }
        // 7 aligned b128 writes, slot XOR-swizzled to spread banks
        const int sw = t & 7;
#pragma unroll
        for (int q = 0; q < 7; ++q) {
            f32x4 vv;
            vv.x = o[4*q+0]; vv.y = o[4*q+1]; vv.z = o[4*q+2]; vv.w = o[4*q+3];
            lds[t * 8 + (q ^ sw)] = vv;
        }
    }
    __syncthreads();

    // Coalesced drain: 1792 float4-chunks per block, 7 per thread.
    const long long totalChunks = PAIRS * 7;
#pragma unroll
    for (int it = 0; it < 7; ++it) {
        const int local = it * 256 + t;          // 0..1791 chunk within block
        const long long c = blockPair * 7 + local;
        if (c < totalChunks) {
            const int p = local / 7;             // pair within block (magic-mul)
            const int q = local - p * 7;         // float4 index within pair
            ((f32x4*)outT)[c] = lds[p * 8 + (q ^ (p & 7))];
        }
    }
}

extern "C" void kernel_launch(void* const* d_in, const int* in_sizes, int n_in,
                              void* d_out, int out_size, void* d_ws, size_t ws_size,
                              hipStream_t stream)
{
    const float* iu   = (const float*)d_in[0];
    const float* io   = (const float*)d_in[1];
    const int*   degu = (const int*)d_in[2];
    const int*   dego = (const int*)d_in[3];
    const float* posw = (const float*)d_in[4];
    const float* negw = (const float*)d_in[5];
    const float* bias = (const float*)d_in[6];
    float* out = (float*)d_out;
    float* ws  = (float*)d_ws;

    hipLaunchKernelGGL(phaseA, dim3(1), dim3(1024), 0, stream,
                       iu, io, posw, negw, bias, ws);

    hipLaunchKernelGGL(phaseBC, dim3(NB + NTAIL, 2), dim3(256), 0, stream,
                       ws, degu, dego, out);
}